// Round 3
// baseline (90.252 us; speedup 1.0000x reference)
//
#include <hip/hip_runtime.h>

// Problem constants: B=1024, C=16, M=4096, N=8192
constexpr int BB = 1024;
constexpr int CC = 16;
constexpr int MM = 4096;
constexpr int NN = 8192;

#define LOG_2PI 1.8378770664093453f

// ---------------- Kernel A: per-(n,c) quadratic coefficients ---------------
// coef2[n*16 + c] = { p2 = a, p1 = -2*a*loc },  a = -0.5/s^2
// k_w[n] = sum_c (a*loc^2 - ln s - 0.5*ln 2pi)
__global__ __launch_bounds__(256) void coeff_kernel(
    const float* __restrict__ locs,   // (C, M)
    const float* __restrict__ scales, // (C, M)
    const int*   __restrict__ edges,  // (C, N)
    float2* __restrict__ coef2,
    float*  __restrict__ k_w)
{
    const int tid = threadIdx.x;
    const int m   = tid & 15;          // n within block's 16 columns
    const int c   = tid >> 4;          // 0..15
    const int n   = blockIdx.x * 16 + m;

    const int   e  = edges[c * NN + n];        // 16 consecutive dwords / lane-group
    const float lc = locs[c * MM + e];         // gather, L2-resident
    const float s  = scales[c * MM + e] + 0.5f;
    const float inv = 1.0f / s;
    const float a   = -0.5f * inv * inv;

    coef2[(size_t)n * 16 + c] = make_float2(a, -2.0f * a * lc);

    __shared__ float lg[256];
    lg[m * 16 + c] = fmaf(a, lc * lc, -__logf(s)) - 0.5f * LOG_2PI;
    __syncthreads();
    if (tid < 16) {
        float K = 0.0f;
#pragma unroll
        for (int cc = 0; cc < 16; ++cc) K += lg[tid * 16 + cc];
        k_w[blockIdx.x * 16 + tid] = K;
    }
}

// ---------------- Kernel B: streaming b-sweep, 2 FMA per (b,n,c) -----------
constexpr int BLOCK   = 256;
constexpr int NPT     = 2;    // columns per thread (float2 store)
constexpr int B_CHUNK = 32;   // rows per block

__global__ __launch_bounds__(BLOCK) void stream_kernel(
    const float*  __restrict__ x,      // (B, C)
    const float2* __restrict__ coef2,  // (N, 16)
    const float*  __restrict__ k_w,    // (N)
    float* __restrict__ out)           // (B, N)
{
    const int tid = threadIdx.x;
    const int n   = blockIdx.x * (BLOCK * NPT) + tid * NPT;  // 2 consecutive cols
    const int b0  = blockIdx.y * B_CHUNK;

    // Stage x slice and x^2: 32 rows x 16 cols
    __shared__ float xs[B_CHUNK * CC];
    __shared__ float xs2[B_CHUNK * CC];
    for (int i = tid; i < B_CHUNK * CC; i += BLOCK) {
        const float v = x[b0 * CC + i];
        xs[i]  = v;
        xs2[i] = v * v;
    }
    __syncthreads();

    // Coefficients for both columns: 2 x 128B contiguous per lane
    float p2a[CC], p1a[CC], p2b[CC], p1b[CC];
#pragma unroll
    for (int c = 0; c < CC; ++c) {
        const float2 qa = coef2[(size_t)n * 16 + c];
        const float2 qb = coef2[(size_t)(n + 1) * 16 + c];
        p2a[c] = qa.x; p1a[c] = qa.y;
        p2b[c] = qb.x; p1b[c] = qb.y;
    }
    const float Ka = k_w[n];
    const float Kb = k_w[n + 1];

    float* outp = out + (size_t)b0 * NN + n;
#pragma unroll 2
    for (int bb = 0; bb < B_CHUNK; ++bb) {
        // 4 independent FMA chains (2 cols x even/odd c)
        float a0 = Ka, a1 = 0.0f, b0a = Kb, b1 = 0.0f;
#pragma unroll
        for (int c = 0; c < CC; c += 2) {
            const float xv0 = xs[bb * CC + c],     x20 = xs2[bb * CC + c];
            const float xv1 = xs[bb * CC + c + 1], x21 = xs2[bb * CC + c + 1];
            a0  = fmaf(x20, p2a[c],     fmaf(xv0, p1a[c],     a0));
            a1  = fmaf(x21, p2a[c + 1], fmaf(xv1, p1a[c + 1], a1));
            b0a = fmaf(x20, p2b[c],     fmaf(xv0, p1b[c],     b0a));
            b1  = fmaf(x21, p2b[c + 1], fmaf(xv1, p1b[c + 1], b1));
        }
        *reinterpret_cast<float2*>(outp + (size_t)bb * NN) =
            make_float2(a0 + a1, b0a + b1);
    }
}

extern "C" void kernel_launch(void* const* d_in, const int* in_sizes, int n_in,
                              void* d_out, int out_size, void* d_ws, size_t ws_size,
                              hipStream_t stream) {
    const float* x      = (const float*)d_in[0];
    const float* locs   = (const float*)d_in[1];
    const float* scales = (const float*)d_in[2];
    const int*   edges  = (const int*)d_in[3];
    float* out = (float*)d_out;

    float2* coef2 = (float2*)d_ws;                       // N*16 float2 = 1 MB
    float*  k_w   = (float*)d_ws + (size_t)2 * CC * NN;  // N floats

    coeff_kernel<<<dim3(NN / 16), dim3(256), 0, stream>>>(
        locs, scales, edges, coef2, k_w);

    stream_kernel<<<dim3(NN / (BLOCK * NPT), BB / B_CHUNK), dim3(BLOCK), 0, stream>>>(
        x, coef2, k_w, out);
}